// Round 1
// baseline (1633.195 us; speedup 1.0000x reference)
//
#include <hip/hip_runtime.h>

#define N_NODES_C 100000
#define N_EDGES_C 1600000
#define FEATS 512
#define HIDDEN 64
#define CLASSES 64
#define DEPTH 10
#define ALPHA 0.1f

#define SCAN_ELEMS 1024   // elements scanned per block (256 threads * 4)
#define SCAN_THREADS 256

// ---------------- degree histogram over dst ----------------
__global__ __launch_bounds__(256) void hist_kernel(const int* __restrict__ dst,
                                                   int* __restrict__ cnt, int E) {
    int i = blockIdx.x * blockDim.x + threadIdx.x;
    int stride = gridDim.x * blockDim.x;
    for (; i < E; i += stride) atomicAdd(&cnt[dst[i]], 1);
}

// ---------------- 3-kernel exclusive scan of cnt -> rowptr ----------------
__global__ __launch_bounds__(SCAN_THREADS) void scan1_kernel(const int* __restrict__ cnt,
                                                             int* __restrict__ rowptr,
                                                             int* __restrict__ partials, int N) {
    __shared__ int sdata[SCAN_THREADS];
    int blk = blockIdx.x;
    int tid = threadIdx.x;
    int base = blk * SCAN_ELEMS + tid * 4;
    int v[4];
    int s = 0;
#pragma unroll
    for (int r = 0; r < 4; ++r) {
        int idx = base + r;
        v[r] = (idx < N) ? cnt[idx] : 0;
        s += v[r];
    }
    sdata[tid] = s;
    __syncthreads();
    // Hillis-Steele inclusive scan over 256 thread sums
    for (int off = 1; off < SCAN_THREADS; off <<= 1) {
        int t = (tid >= off) ? sdata[tid - off] : 0;
        __syncthreads();
        sdata[tid] += t;
        __syncthreads();
    }
    int excl = sdata[tid] - s;  // exclusive prefix of this thread within block
    if (tid == SCAN_THREADS - 1) partials[blk] = sdata[tid];
    int run = excl;
#pragma unroll
    for (int r = 0; r < 4; ++r) {
        int idx = base + r;
        if (idx < N) rowptr[idx] = run;
        run += v[r];
    }
}

__global__ __launch_bounds__(1024) void scan2_kernel(int* __restrict__ partials, int nb) {
    __shared__ int sdata[1024];
    int tid = threadIdx.x;
    int v = (tid < nb) ? partials[tid] : 0;
    sdata[tid] = v;
    __syncthreads();
    for (int off = 1; off < 1024; off <<= 1) {
        int t = (tid >= off) ? sdata[tid - off] : 0;
        __syncthreads();
        sdata[tid] += t;
        __syncthreads();
    }
    if (tid < nb) partials[tid] = sdata[tid] - v;  // exclusive
}

__global__ __launch_bounds__(256) void scan3_kernel(int* __restrict__ rowptr,
                                                    const int* __restrict__ partials,
                                                    int N, int E) {
    int i = blockIdx.x * blockDim.x + threadIdx.x;
    int stride = gridDim.x * blockDim.x;
    for (; i < N; i += stride) rowptr[i] += partials[i / SCAN_ELEMS];
    if (blockIdx.x == 0 && threadIdx.x == 0) rowptr[N] = E;
}

// ---------------- inv_sqrt_deg + cursor init ----------------
__global__ __launch_bounds__(256) void norm_init_kernel(const int* __restrict__ cnt,
                                                        float* __restrict__ inv_sqrt,
                                                        const int* __restrict__ rowptr,
                                                        int* __restrict__ cursor, int N) {
    int i = blockIdx.x * blockDim.x + threadIdx.x;
    int stride = gridDim.x * blockDim.x;
    for (; i < N; i += stride) {
        int c = cnt[i];
        float d = (c < 1) ? 1.0f : (float)c;
        inv_sqrt[i] = rsqrtf(d);
        cursor[i] = rowptr[i];
    }
}

// ---------------- scatter edges into CSR (counting sort by dst) ----------------
__global__ __launch_bounds__(256) void scatter_kernel(const int* __restrict__ src,
                                                      const int* __restrict__ dst,
                                                      const float* __restrict__ inv_sqrt,
                                                      int* __restrict__ cursor,
                                                      int* __restrict__ csr_src,
                                                      float* __restrict__ csr_norm, int E) {
    int i = blockIdx.x * blockDim.x + threadIdx.x;
    int stride = gridDim.x * blockDim.x;
    for (; i < E; i += stride) {
        int s = src[i];
        int d = dst[i];
        int pos = atomicAdd(&cursor[d], 1);
        csr_src[pos] = s;
        // fold the (1-alpha) propagation scale into the edge weight
        csr_norm[pos] = (1.0f - ALPHA) * inv_sqrt[s] * inv_sqrt[d];
    }
}

// ---------------- MLP: h0 = relu(x@W1+b1)@W2 + b2 ----------------
// one 64-lane wave per node; lane = output feature
__global__ __launch_bounds__(256) void mlp_kernel(const float* __restrict__ x,
                                                  const float* __restrict__ W1,
                                                  const float* __restrict__ b1,
                                                  const float* __restrict__ W2,
                                                  const float* __restrict__ b2,
                                                  float* __restrict__ h0, int N) {
    __shared__ float xs[4][FEATS];
    __shared__ float hs[4][HIDDEN];
    int wave = threadIdx.x >> 6;
    int lane = threadIdx.x & 63;
    int n = blockIdx.x * 4 + wave;   // grid sized so n < N always (N % 4 == 0)

    // stage x row (512 f32) into LDS, vectorized: 128 float4, 2 per lane
    const float4* xrow = (const float4*)(x + (size_t)n * FEATS);
    ((float4*)xs[wave])[lane] = xrow[lane];
    ((float4*)xs[wave])[lane + 64] = xrow[lane + 64];
    __syncthreads();

    float acc = b1[lane];
#pragma unroll 8
    for (int k = 0; k < FEATS; ++k) {
        acc += xs[wave][k] * W1[k * HIDDEN + lane];  // W1 col read coalesced across lanes
    }
    acc = fmaxf(acc, 0.0f);
    hs[wave][lane] = acc;
    __syncthreads();

    float out = b2[lane];
#pragma unroll
    for (int k = 0; k < HIDDEN; ++k) {
        out += hs[wave][k] * W2[k * CLASSES + lane];
    }
    h0[(size_t)n * CLASSES + lane] = out;
}

// ---------------- propagation: h_out = alpha*h0 + sum_e w_e * h_in[src_e] ----------------
// one wave per node, lane = feature; edge (src, w) batches shared via shuffles
__global__ __launch_bounds__(256) void prop_kernel(const int* __restrict__ rowptr,
                                                   const int* __restrict__ csr_src,
                                                   const float* __restrict__ csr_norm,
                                                   const float* __restrict__ h_in,
                                                   const float* __restrict__ h0,
                                                   float* __restrict__ h_out, int N) {
    int wid = (blockIdx.x * blockDim.x + threadIdx.x) >> 6;
    int lane = threadIdx.x & 63;
    if (wid >= N) return;
    int base = rowptr[wid];
    int end = rowptr[wid + 1];
    float acc = ALPHA * h0[(size_t)wid * CLASSES + lane];
    for (int b = base; b < end; b += 64) {
        int m = end - b;
        if (m > 64) m = 64;
        int s = 0;
        float w = 0.0f;
        if (lane < m) {
            s = csr_src[b + lane];
            w = csr_norm[b + lane];
        }
        for (int t = 0; t < m; ++t) {
            int ss = __shfl(s, t);
            float ww = __shfl(w, t);
            acc += ww * h_in[(size_t)ss * CLASSES + lane];  // 256B coalesced row gather
        }
    }
    h_out[(size_t)wid * CLASSES + lane] = acc;
}

extern "C" void kernel_launch(void* const* d_in, const int* in_sizes, int n_in,
                              void* d_out, int out_size, void* d_ws, size_t ws_size,
                              hipStream_t stream) {
    const float* x = (const float*)d_in[0];
    const int* edges = (const int*)d_in[1];
    const float* W1 = (const float*)d_in[2];
    const float* b1 = (const float*)d_in[3];
    const float* W2 = (const float*)d_in[4];
    const float* b2 = (const float*)d_in[5];
    float* out = (float*)d_out;

    const int N = in_sizes[0] / FEATS;   // 100000
    const int E = in_sizes[1] / 2;       // 1600000
    const int* src = edges;
    const int* dst = edges + E;

    // ---- workspace carve-up (aligned to 256B) ----
    char* ws = (char*)d_ws;
    size_t off = 0;
    auto alloc = [&](size_t bytes) {
        char* p = ws + off;
        off = (off + bytes + 255) & ~(size_t)255;
        return p;
    };
    int* cnt = (int*)alloc((size_t)N * 4);
    int* rowptr = (int*)alloc((size_t)(N + 1) * 4);
    int* cursor = (int*)alloc((size_t)N * 4);
    int* partials = (int*)alloc(1024 * 4);
    float* inv_sqrt = (float*)alloc((size_t)N * 4);
    int* csr_src = (int*)alloc((size_t)E * 4);
    float* csr_norm = (float*)alloc((size_t)E * 4);
    float* h0 = (float*)alloc((size_t)N * CLASSES * 4);
    float* hB = (float*)alloc((size_t)N * CLASSES * 4);
    (void)ws_size;

    // ---- CSR build ----
    hipMemsetAsync(cnt, 0, (size_t)N * 4, stream);
    hist_kernel<<<1024, 256, 0, stream>>>(dst, cnt, E);
    int nb = (N + SCAN_ELEMS - 1) / SCAN_ELEMS;  // 98
    scan1_kernel<<<nb, SCAN_THREADS, 0, stream>>>(cnt, rowptr, partials, N);
    scan2_kernel<<<1, 1024, 0, stream>>>(partials, nb);
    scan3_kernel<<<256, 256, 0, stream>>>(rowptr, partials, N, E);
    norm_init_kernel<<<256, 256, 0, stream>>>(cnt, inv_sqrt, rowptr, cursor, N);
    scatter_kernel<<<1024, 256, 0, stream>>>(src, dst, inv_sqrt, cursor, csr_src, csr_norm, E);

    // ---- MLP (h0) ----
    mlp_kernel<<<N / 4, 256, 0, stream>>>(x, W1, b1, W2, b2, h0, N);

    // ---- 10 propagation rounds, ping-pong {hB, d_out}; DEPTH even -> ends in d_out ----
    int blocks = (N * 64 + 255) / 256;
    for (int d = 0; d < DEPTH; ++d) {
        const float* hin = (d == 0) ? h0 : ((d & 1) ? hB : out);
        float* hout = (d & 1) ? out : hB;
        prop_kernel<<<blocks, 256, 0, stream>>>(rowptr, csr_src, csr_norm, hin, h0, hout, N);
    }
}

// Round 2
// 891.534 us; speedup vs baseline: 1.8319x; 1.8319x over previous
//
#include <hip/hip_runtime.h>

#define FEATS 512
#define HIDDEN 64
#define CLASSES 64
#define DEPTH 10
#define ALPHA 0.1f

#define SCAN_ELEMS 1024
#define SCAN_THREADS 256

typedef __attribute__((ext_vector_type(8))) short short8;
typedef __attribute__((ext_vector_type(4))) float f32x4;

__device__ __forceinline__ unsigned short bf16_hi(float f) {
    unsigned u = __float_as_uint(f);
    unsigned r = u + 0x7FFF + ((u >> 16) & 1);   // RNE
    return (unsigned short)(r >> 16);
}
__device__ __forceinline__ float bf16_tof(unsigned short h) {
    return __uint_as_float(((unsigned)h) << 16);
}

// ---------------- degree histogram over dst ----------------
__global__ __launch_bounds__(256) void hist_kernel(const int* __restrict__ dst,
                                                   int* __restrict__ cnt, int E) {
    int i = blockIdx.x * blockDim.x + threadIdx.x;
    int stride = gridDim.x * blockDim.x;
    for (; i < E; i += stride) atomicAdd(&cnt[dst[i]], 1);
}

// ---------------- 3-kernel exclusive scan of cnt -> rowptr ----------------
__global__ __launch_bounds__(SCAN_THREADS) void scan1_kernel(const int* __restrict__ cnt,
                                                             int* __restrict__ rowptr,
                                                             int* __restrict__ partials, int N) {
    __shared__ int sdata[SCAN_THREADS];
    int blk = blockIdx.x;
    int tid = threadIdx.x;
    int base = blk * SCAN_ELEMS + tid * 4;
    int v[4];
    int s = 0;
#pragma unroll
    for (int r = 0; r < 4; ++r) {
        int idx = base + r;
        v[r] = (idx < N) ? cnt[idx] : 0;
        s += v[r];
    }
    sdata[tid] = s;
    __syncthreads();
    for (int off = 1; off < SCAN_THREADS; off <<= 1) {
        int t = (tid >= off) ? sdata[tid - off] : 0;
        __syncthreads();
        sdata[tid] += t;
        __syncthreads();
    }
    int excl = sdata[tid] - s;
    if (tid == SCAN_THREADS - 1) partials[blk] = sdata[tid];
    int run = excl;
#pragma unroll
    for (int r = 0; r < 4; ++r) {
        int idx = base + r;
        if (idx < N) rowptr[idx] = run;
        run += v[r];
    }
}

__global__ __launch_bounds__(1024) void scan2_kernel(int* __restrict__ partials, int nb) {
    __shared__ int sdata[1024];
    int tid = threadIdx.x;
    int v = (tid < nb) ? partials[tid] : 0;
    sdata[tid] = v;
    __syncthreads();
    for (int off = 1; off < 1024; off <<= 1) {
        int t = (tid >= off) ? sdata[tid - off] : 0;
        __syncthreads();
        sdata[tid] += t;
        __syncthreads();
    }
    if (tid < nb) partials[tid] = sdata[tid] - v;
}

__global__ __launch_bounds__(256) void scan3_kernel(int* __restrict__ rowptr,
                                                    const int* __restrict__ partials,
                                                    int N, int E) {
    int i = blockIdx.x * blockDim.x + threadIdx.x;
    int stride = gridDim.x * blockDim.x;
    for (; i < N; i += stride) rowptr[i] += partials[i / SCAN_ELEMS];
    if (blockIdx.x == 0 && threadIdx.x == 0) rowptr[N] = E;
}

// ---------------- inv_sqrt_deg + cursor init ----------------
__global__ __launch_bounds__(256) void norm_init_kernel(const int* __restrict__ cnt,
                                                        float* __restrict__ inv_sqrt,
                                                        const int* __restrict__ rowptr,
                                                        int* __restrict__ cursor, int N) {
    int i = blockIdx.x * blockDim.x + threadIdx.x;
    int stride = gridDim.x * blockDim.x;
    for (; i < N; i += stride) {
        int c = cnt[i];
        float d = (c < 1) ? 1.0f : (float)c;
        inv_sqrt[i] = rsqrtf(d);
        cursor[i] = rowptr[i];
    }
}

// ---------------- scatter edges into CSR ----------------
__global__ __launch_bounds__(256) void scatter_kernel(const int* __restrict__ src,
                                                      const int* __restrict__ dst,
                                                      const float* __restrict__ inv_sqrt,
                                                      int* __restrict__ cursor,
                                                      int* __restrict__ csr_src,
                                                      float* __restrict__ csr_norm, int E) {
    int i = blockIdx.x * blockDim.x + threadIdx.x;
    int stride = gridDim.x * blockDim.x;
    for (; i < E; i += stride) {
        int s = src[i];
        int d = dst[i];
        int pos = atomicAdd(&cursor[d], 1);
        csr_src[pos] = s;
        csr_norm[pos] = (1.0f - ALPHA) * inv_sqrt[s] * inv_sqrt[d];
    }
}

// ---------------- pack W1/W2 into MFMA B-fragment order, split bf16 hi/lo ----
// layout: elem (ks, f, lane, i) at ((ks*4+f)*64 + lane)*8 + i
//   maps W[ks*32 + (lane>>4)*8 + i][f*16 + (lane&15)]
__global__ __launch_bounds__(256) void pack_w_kernel(const float* __restrict__ W1,
                                                     const float* __restrict__ W2,
                                                     unsigned short* __restrict__ w1h,
                                                     unsigned short* __restrict__ w1l,
                                                     unsigned short* __restrict__ w2h,
                                                     unsigned short* __restrict__ w2l) {
    int id = blockIdx.x * blockDim.x + threadIdx.x;
    if (id < 4096) {  // W1: 16 ksteps * 4 frags * 64 lanes
        int lane = id & 63, f = (id >> 6) & 3, ks = id >> 8;
        int col = f * 16 + (lane & 15);
        int k0 = ks * 32 + (lane >> 4) * 8;
#pragma unroll
        for (int i = 0; i < 8; ++i) {
            float v = W1[(k0 + i) * HIDDEN + col];
            unsigned short h = bf16_hi(v);
            w1h[id * 8 + i] = h;
            w1l[id * 8 + i] = bf16_hi(v - bf16_tof(h));
        }
    } else if (id < 4096 + 512) {  // W2: 2 ksteps * 4 frags * 64 lanes
        int p = id - 4096;
        int lane = p & 63, f = (p >> 6) & 3, ks = p >> 8;
        int col = f * 16 + (lane & 15);
        int k0 = ks * 32 + (lane >> 4) * 8;
#pragma unroll
        for (int i = 0; i < 8; ++i) {
            float v = W2[(k0 + i) * CLASSES + col];
            unsigned short h = bf16_hi(v);
            w2h[p * 8 + i] = h;
            w2l[p * 8 + i] = bf16_hi(v - bf16_tof(h));
        }
    }
}

// ---------------- MLP via split-bf16 MFMA: h0 = relu(x@W1+b1)@W2+b2 ---------
// one wave per 16-node tile; A: row=lane&15, k=(lane>>4)*8+i; C: col=lane&15, row=(lane>>4)*4+r
__global__ __launch_bounds__(256) void mlp_mfma_kernel(const float* __restrict__ x,
                                                       const unsigned short* __restrict__ w1h,
                                                       const unsigned short* __restrict__ w1l,
                                                       const float* __restrict__ b1,
                                                       const unsigned short* __restrict__ w2h,
                                                       const unsigned short* __restrict__ w2l,
                                                       const float* __restrict__ b2,
                                                       float* __restrict__ h0, int N) {
    __shared__ float hs[4][16][68];  // pad 68: 16B-aligned rows, ~2-way banks only
    int wave = threadIdx.x >> 6;
    int lane = threadIdx.x & 63;
    int tile = blockIdx.x * 4 + wave;
    if (tile * 16 >= N) return;

    int row = lane & 15;
    int koff = (lane >> 4) * 8;
    const short8* w1hv = (const short8*)w1h;
    const short8* w1lv = (const short8*)w1l;
    const short8* w2hv = (const short8*)w2h;
    const short8* w2lv = (const short8*)w2l;

    f32x4 c[4] = {};
    const float* xrow = x + (size_t)(tile * 16 + row) * FEATS + koff;
#pragma unroll 4
    for (int ks = 0; ks < 16; ++ks) {
        float4 a0 = *(const float4*)(xrow + ks * 32);
        float4 a1 = *(const float4*)(xrow + ks * 32 + 4);
        float av[8] = {a0.x, a0.y, a0.z, a0.w, a1.x, a1.y, a1.z, a1.w};
        short8 ah, al;
#pragma unroll
        for (int j = 0; j < 8; ++j) {
            unsigned short h = bf16_hi(av[j]);
            ah[j] = (short)h;
            al[j] = (short)bf16_hi(av[j] - bf16_tof(h));
        }
#pragma unroll
        for (int f = 0; f < 4; ++f) {
            short8 bh = w1hv[(ks * 4 + f) * 64 + lane];
            short8 bl = w1lv[(ks * 4 + f) * 64 + lane];
            c[f] = __builtin_amdgcn_mfma_f32_16x16x32_bf16(ah, bh, c[f], 0, 0, 0);
            c[f] = __builtin_amdgcn_mfma_f32_16x16x32_bf16(ah, bl, c[f], 0, 0, 0);
            c[f] = __builtin_amdgcn_mfma_f32_16x16x32_bf16(al, bh, c[f], 0, 0, 0);
        }
    }
    // bias + relu -> LDS tile (within-wave only; no barrier needed)
#pragma unroll
    for (int f = 0; f < 4; ++f) {
        float bias = b1[f * 16 + (lane & 15)];
#pragma unroll
        for (int r = 0; r < 4; ++r) {
            hs[wave][(lane >> 4) * 4 + r][f * 16 + (lane & 15)] = fmaxf(c[f][r] + bias, 0.0f);
        }
    }

    f32x4 c2[4] = {};
#pragma unroll
    for (int ks = 0; ks < 2; ++ks) {
        float4 a0 = *(const float4*)&hs[wave][row][ks * 32 + koff];
        float4 a1 = *(const float4*)&hs[wave][row][ks * 32 + koff + 4];
        float av[8] = {a0.x, a0.y, a0.z, a0.w, a1.x, a1.y, a1.z, a1.w};
        short8 ah, al;
#pragma unroll
        for (int j = 0; j < 8; ++j) {
            unsigned short h = bf16_hi(av[j]);
            ah[j] = (short)h;
            al[j] = (short)bf16_hi(av[j] - bf16_tof(h));
        }
#pragma unroll
        for (int f = 0; f < 4; ++f) {
            short8 bh = w2hv[(ks * 4 + f) * 64 + lane];
            short8 bl = w2lv[(ks * 4 + f) * 64 + lane];
            c2[f] = __builtin_amdgcn_mfma_f32_16x16x32_bf16(ah, bh, c2[f], 0, 0, 0);
            c2[f] = __builtin_amdgcn_mfma_f32_16x16x32_bf16(ah, bl, c2[f], 0, 0, 0);
            c2[f] = __builtin_amdgcn_mfma_f32_16x16x32_bf16(al, bh, c2[f], 0, 0, 0);
        }
    }
#pragma unroll
    for (int f = 0; f < 4; ++f) {
        float bias = b2[f * 16 + (lane & 15)];
#pragma unroll
        for (int r = 0; r < 4; ++r) {
            int n = tile * 16 + (lane >> 4) * 4 + r;
            h0[(size_t)n * CLASSES + f * 16 + (lane & 15)] = c2[f][r] + bias;
        }
    }
}

// ---------------- propagation: h_out = alpha*h0 + sum_e w_e * h_in[src_e] ----
__global__ __launch_bounds__(256) void prop_kernel(const int* __restrict__ rowptr,
                                                   const int* __restrict__ csr_src,
                                                   const float* __restrict__ csr_norm,
                                                   const float* __restrict__ h_in,
                                                   const float* __restrict__ h0,
                                                   float* __restrict__ h_out, int N) {
    int wid = (blockIdx.x * blockDim.x + threadIdx.x) >> 6;
    int lane = threadIdx.x & 63;
    if (wid >= N) return;
    int base = rowptr[wid];
    int end = rowptr[wid + 1];
    float acc = ALPHA * h0[(size_t)wid * CLASSES + lane];
    for (int b = base; b < end; b += 64) {
        int m = end - b;
        if (m > 64) m = 64;
        int s = 0;
        float w = 0.0f;
        if (lane < m) {
            s = csr_src[b + lane];
            w = csr_norm[b + lane];
        }
        int t = 0;
        for (; t + 8 <= m; t += 8) {
            int ss[8];
            float ww[8], v[8];
#pragma unroll
            for (int j = 0; j < 8; ++j) {
                ss[j] = __shfl(s, t + j);
                ww[j] = __shfl(w, t + j);
            }
#pragma unroll
            for (int j = 0; j < 8; ++j) v[j] = h_in[(size_t)ss[j] * CLASSES + lane];
#pragma unroll
            for (int j = 0; j < 8; ++j) acc += ww[j] * v[j];
        }
        for (; t < m; ++t) {
            int ss = __shfl(s, t);
            float ww = __shfl(w, t);
            acc += ww * h_in[(size_t)ss * CLASSES + lane];
        }
    }
    h_out[(size_t)wid * CLASSES + lane] = acc;
}

extern "C" void kernel_launch(void* const* d_in, const int* in_sizes, int n_in,
                              void* d_out, int out_size, void* d_ws, size_t ws_size,
                              hipStream_t stream) {
    const float* x = (const float*)d_in[0];
    const int* edges = (const int*)d_in[1];
    const float* W1 = (const float*)d_in[2];
    const float* b1 = (const float*)d_in[3];
    const float* W2 = (const float*)d_in[4];
    const float* b2 = (const float*)d_in[5];
    float* out = (float*)d_out;

    const int N = in_sizes[0] / FEATS;   // 100000
    const int E = in_sizes[1] / 2;       // 1600000
    const int* src = edges;
    const int* dst = edges + E;

    char* ws = (char*)d_ws;
    size_t off = 0;
    auto alloc = [&](size_t bytes) {
        char* p = ws + off;
        off = (off + bytes + 255) & ~(size_t)255;
        return p;
    };
    int* cnt = (int*)alloc((size_t)N * 4);
    int* rowptr = (int*)alloc((size_t)(N + 1) * 4);
    int* cursor = (int*)alloc((size_t)N * 4);
    int* partials = (int*)alloc(1024 * 4);
    float* inv_sqrt = (float*)alloc((size_t)N * 4);
    int* csr_src = (int*)alloc((size_t)E * 4);
    float* csr_norm = (float*)alloc((size_t)E * 4);
    float* h0 = (float*)alloc((size_t)N * CLASSES * 4);
    float* hB = (float*)alloc((size_t)N * CLASSES * 4);
    unsigned short* w1h = (unsigned short*)alloc(4096 * 8 * 2);
    unsigned short* w1l = (unsigned short*)alloc(4096 * 8 * 2);
    unsigned short* w2h = (unsigned short*)alloc(512 * 8 * 2);
    unsigned short* w2l = (unsigned short*)alloc(512 * 8 * 2);
    (void)ws_size;

    // ---- CSR build ----
    hipMemsetAsync(cnt, 0, (size_t)N * 4, stream);
    hist_kernel<<<1024, 256, 0, stream>>>(dst, cnt, E);
    int nb = (N + SCAN_ELEMS - 1) / SCAN_ELEMS;
    scan1_kernel<<<nb, SCAN_THREADS, 0, stream>>>(cnt, rowptr, partials, N);
    scan2_kernel<<<1, 1024, 0, stream>>>(partials, nb);
    scan3_kernel<<<256, 256, 0, stream>>>(rowptr, partials, N, E);
    norm_init_kernel<<<256, 256, 0, stream>>>(cnt, inv_sqrt, rowptr, cursor, N);
    scatter_kernel<<<1024, 256, 0, stream>>>(src, dst, inv_sqrt, cursor, csr_src, csr_norm, E);

    // ---- MLP ----
    pack_w_kernel<<<18, 256, 0, stream>>>(W1, W2, w1h, w1l, w2h, w2l);
    int tiles = (N + 15) / 16;
    mlp_mfma_kernel<<<(tiles + 3) / 4, 256, 0, stream>>>(x, w1h, w1l, b1, w2h, w2l, b2, h0, N);

    // ---- 10 propagation rounds ----
    int blocks = (N * 64 + 255) / 256;
    for (int d = 0; d < DEPTH; ++d) {
        const float* hin = (d == 0) ? h0 : ((d & 1) ? hB : out);
        float* hout = (d & 1) ? out : hB;
        prop_kernel<<<blocks, 256, 0, stream>>>(rowptr, csr_src, csr_norm, hin, h0, hout, N);
    }
}

// Round 3
// 683.530 us; speedup vs baseline: 2.3894x; 1.3043x over previous
//
#include <hip/hip_runtime.h>
#include <hip/hip_fp16.h>

#define FEATS 512
#define HIDDEN 64
#define CLASSES 64
#define DEPTH 10
#define ALPHA 0.1f

#define NB_C 1563        // ceil(100000 / 64) buckets of 64 nodes
#define K3_CHUNK 8192
#define K3_THREADS 512

typedef __attribute__((ext_vector_type(8))) short short8;
typedef __attribute__((ext_vector_type(4))) float f32x4;

__device__ __forceinline__ unsigned short bf16_hi(float f) {
    unsigned u = __float_as_uint(f);
    unsigned r = u + 0x7FFF + ((u >> 16) & 1);   // RNE
    return (unsigned short)(r >> 16);
}
__device__ __forceinline__ float bf16_tof(unsigned short h) {
    return __uint_as_float(((unsigned)h) << 16);
}

// ---------------- K1: bucket histogram (LDS-aggregated) ----------------
__global__ __launch_bounds__(256) void bucket_hist_kernel(const int* __restrict__ dst,
                                                          int* __restrict__ bcnt,
                                                          int NB, int E) {
    __shared__ int h[NB_C];
    for (int j = threadIdx.x; j < NB; j += 256) h[j] = 0;
    __syncthreads();
    int i = blockIdx.x * 256 + threadIdx.x;
    int stride = gridDim.x * 256;
    for (; i < E; i += stride) atomicAdd(&h[dst[i] >> 6], 1);
    __syncthreads();
    for (int j = threadIdx.x; j < NB; j += 256) {
        int v = h[j];
        if (v) atomicAdd(&bcnt[j], v);
    }
}

// ---------------- K2: scan bucket counts -> bptr, gcursor ----------------
__global__ __launch_bounds__(1024) void bucket_scan_kernel(const int* __restrict__ bcnt,
                                                           int* __restrict__ bptr,
                                                           int* __restrict__ gcur,
                                                           int* __restrict__ rowptr,
                                                           int NB, int N, int E) {
    __shared__ int sd[1024];
    int t = threadIdx.x;
    int i0 = 2 * t, i1 = 2 * t + 1;
    int a = (i0 < NB) ? bcnt[i0] : 0;
    int b = (i1 < NB) ? bcnt[i1] : 0;
    int s = a + b;
    sd[t] = s;
    __syncthreads();
    for (int off = 1; off < 1024; off <<= 1) {
        int v = (t >= off) ? sd[t - off] : 0;
        __syncthreads();
        sd[t] += v;
        __syncthreads();
    }
    int excl = sd[t] - s;
    if (i0 < NB) { bptr[i0] = excl;     gcur[i0] = excl; }
    if (i1 < NB) { bptr[i1] = excl + a; gcur[i1] = excl + a; }
    if (t == 0) { bptr[NB] = E; rowptr[N] = E; }
}

// ---------------- K3: partition edges into buckets (block-reserved ranges) ----
__global__ __launch_bounds__(K3_THREADS) void bucket_scatter_kernel(const int* __restrict__ src,
                                                                    const int* __restrict__ dst,
                                                                    int* __restrict__ gcur,
                                                                    int2* __restrict__ part,
                                                                    int NB, int E) {
    __shared__ int hist[NB_C];
    __shared__ int base[NB_C];
    int cbase = blockIdx.x * K3_CHUNK;
    for (int j = threadIdx.x; j < NB; j += K3_THREADS) hist[j] = 0;
    __syncthreads();
    for (int k = 0; k < K3_CHUNK; k += K3_THREADS) {
        int i = cbase + k + threadIdx.x;
        if (i < E) atomicAdd(&hist[dst[i] >> 6], 1);
    }
    __syncthreads();
    for (int j = threadIdx.x; j < NB; j += K3_THREADS) {
        int h = hist[j];
        base[j] = (h > 0) ? atomicAdd(&gcur[j], h) : 0;
        hist[j] = 0;   // reuse as local cursor
    }
    __syncthreads();
    for (int k = 0; k < K3_CHUNK; k += K3_THREADS) {
        int i = cbase + k + threadIdx.x;
        if (i < E) {
            int d = dst[i];
            int j = d >> 6;
            int off = atomicAdd(&hist[j], 1);
            part[(size_t)(base[j] + off)] = make_int2(src[i], d);
        }
    }
}

// ---------------- K4: per-bucket exact CSR + degrees + inv_sqrt ----------------
__global__ __launch_bounds__(128) void part_to_csr_kernel(const int* __restrict__ bptr,
                                                          const int2* __restrict__ part,
                                                          int* __restrict__ rowptr,
                                                          float* __restrict__ inv_sqrt,
                                                          int* __restrict__ csr_src,
                                                          int N) {
    __shared__ int cnt[64];
    __shared__ int cur[64];
    int b = blockIdx.x;
    int lo = b << 6;
    int tid = threadIdx.x;
    int p0 = bptr[b], p1 = bptr[b + 1];
    if (tid < 64) cnt[tid] = 0;
    __syncthreads();
    for (int i = p0 + tid; i < p1; i += 128) {
        int2 e = part[i];
        atomicAdd(&cnt[e.y - lo], 1);
    }
    __syncthreads();
    if (tid < 64) {
        int v = cnt[tid];
        int incl = v;
#pragma unroll
        for (int off = 1; off < 64; off <<= 1) {
            int t = __shfl_up(incl, off);
            if (tid >= off) incl += t;
        }
        int excl = incl - v;
        if (lo + tid < N) {
            rowptr[lo + tid] = p0 + excl;
            inv_sqrt[lo + tid] = rsqrtf((float)(v < 1 ? 1 : v));
        }
        cur[tid] = excl;
    }
    __syncthreads();
    for (int i = p0 + tid; i < p1; i += 128) {
        int2 e = part[i];
        int off = atomicAdd(&cur[e.y - lo], 1);
        csr_src[p0 + off] = e.x;
    }
}

// ---------------- pack W1/W2 into MFMA B-fragment order, split bf16 hi/lo ----
__global__ __launch_bounds__(256) void pack_w_kernel(const float* __restrict__ W1,
                                                     const float* __restrict__ W2,
                                                     unsigned short* __restrict__ w1h,
                                                     unsigned short* __restrict__ w1l,
                                                     unsigned short* __restrict__ w2h,
                                                     unsigned short* __restrict__ w2l) {
    int id = blockIdx.x * blockDim.x + threadIdx.x;
    if (id < 4096) {
        int lane = id & 63, f = (id >> 6) & 3, ks = id >> 8;
        int col = f * 16 + (lane & 15);
        int k0 = ks * 32 + (lane >> 4) * 8;
#pragma unroll
        for (int i = 0; i < 8; ++i) {
            float v = W1[(k0 + i) * HIDDEN + col];
            unsigned short h = bf16_hi(v);
            w1h[id * 8 + i] = h;
            w1l[id * 8 + i] = bf16_hi(v - bf16_tof(h));
        }
    } else if (id < 4096 + 512) {
        int p = id - 4096;
        int lane = p & 63, f = (p >> 6) & 3, ks = p >> 8;
        int col = f * 16 + (lane & 15);
        int k0 = ks * 32 + (lane >> 4) * 8;
#pragma unroll
        for (int i = 0; i < 8; ++i) {
            float v = W2[(k0 + i) * CLASSES + col];
            unsigned short h = bf16_hi(v);
            w2h[p * 8 + i] = h;
            w2l[p * 8 + i] = bf16_hi(v - bf16_tof(h));
        }
    }
}

// ---------------- MLP via split-bf16 MFMA: h0 = relu(x@W1+b1)@W2+b2 (fp16 out)
__global__ __launch_bounds__(256) void mlp_mfma_kernel(const float* __restrict__ x,
                                                       const unsigned short* __restrict__ w1h,
                                                       const unsigned short* __restrict__ w1l,
                                                       const float* __restrict__ b1,
                                                       const unsigned short* __restrict__ w2h,
                                                       const unsigned short* __restrict__ w2l,
                                                       const float* __restrict__ b2,
                                                       __half* __restrict__ h0h, int N) {
    __shared__ float hs[4][16][68];
    int wave = threadIdx.x >> 6;
    int lane = threadIdx.x & 63;
    int tile = blockIdx.x * 4 + wave;
    if (tile * 16 >= N) return;

    int row = lane & 15;
    int koff = (lane >> 4) * 8;
    const short8* w1hv = (const short8*)w1h;
    const short8* w1lv = (const short8*)w1l;
    const short8* w2hv = (const short8*)w2h;
    const short8* w2lv = (const short8*)w2l;

    f32x4 c[4] = {};
    const float* xrow = x + (size_t)(tile * 16 + row) * FEATS + koff;
#pragma unroll 4
    for (int ks = 0; ks < 16; ++ks) {
        float4 a0 = *(const float4*)(xrow + ks * 32);
        float4 a1 = *(const float4*)(xrow + ks * 32 + 4);
        float av[8] = {a0.x, a0.y, a0.z, a0.w, a1.x, a1.y, a1.z, a1.w};
        short8 ah, al;
#pragma unroll
        for (int j = 0; j < 8; ++j) {
            unsigned short h = bf16_hi(av[j]);
            ah[j] = (short)h;
            al[j] = (short)bf16_hi(av[j] - bf16_tof(h));
        }
#pragma unroll
        for (int f = 0; f < 4; ++f) {
            short8 bh = w1hv[(ks * 4 + f) * 64 + lane];
            short8 bl = w1lv[(ks * 4 + f) * 64 + lane];
            c[f] = __builtin_amdgcn_mfma_f32_16x16x32_bf16(ah, bh, c[f], 0, 0, 0);
            c[f] = __builtin_amdgcn_mfma_f32_16x16x32_bf16(ah, bl, c[f], 0, 0, 0);
            c[f] = __builtin_amdgcn_mfma_f32_16x16x32_bf16(al, bh, c[f], 0, 0, 0);
        }
    }
#pragma unroll
    for (int f = 0; f < 4; ++f) {
        float bias = b1[f * 16 + (lane & 15)];
#pragma unroll
        for (int r = 0; r < 4; ++r) {
            hs[wave][(lane >> 4) * 4 + r][f * 16 + (lane & 15)] = fmaxf(c[f][r] + bias, 0.0f);
        }
    }

    f32x4 c2[4] = {};
#pragma unroll
    for (int ks = 0; ks < 2; ++ks) {
        float4 a0 = *(const float4*)&hs[wave][row][ks * 32 + koff];
        float4 a1 = *(const float4*)&hs[wave][row][ks * 32 + koff + 4];
        float av[8] = {a0.x, a0.y, a0.z, a0.w, a1.x, a1.y, a1.z, a1.w};
        short8 ah, al;
#pragma unroll
        for (int j = 0; j < 8; ++j) {
            unsigned short h = bf16_hi(av[j]);
            ah[j] = (short)h;
            al[j] = (short)bf16_hi(av[j] - bf16_tof(h));
        }
#pragma unroll
        for (int f = 0; f < 4; ++f) {
            short8 bh = w2hv[(ks * 4 + f) * 64 + lane];
            short8 bl = w2lv[(ks * 4 + f) * 64 + lane];
            c2[f] = __builtin_amdgcn_mfma_f32_16x16x32_bf16(ah, bh, c2[f], 0, 0, 0);
            c2[f] = __builtin_amdgcn_mfma_f32_16x16x32_bf16(ah, bl, c2[f], 0, 0, 0);
            c2[f] = __builtin_amdgcn_mfma_f32_16x16x32_bf16(al, bh, c2[f], 0, 0, 0);
        }
    }
#pragma unroll
    for (int f = 0; f < 4; ++f) {
        float bias = b2[f * 16 + (lane & 15)];
#pragma unroll
        for (int r = 0; r < 4; ++r) {
            int n = tile * 16 + (lane >> 4) * 4 + r;
            h0h[(size_t)n * CLASSES + f * 16 + (lane & 15)] = __float2half(c2[f][r] + bias);
        }
    }
}

// ---------------- u0 = h0 * inv_sqrt (fp16) ----------------
__global__ __launch_bounds__(256) void u0_kernel(const __half* __restrict__ h0h,
                                                 const float* __restrict__ is,
                                                 __half* __restrict__ u, int total2) {
    int i = blockIdx.x * blockDim.x + threadIdx.x;
    int stride = gridDim.x * blockDim.x;
    const __half2* s = (const __half2*)h0h;
    __half2* d = (__half2*)u;
    for (; i < total2; i += stride) {
        float isv = is[i >> 5];      // pair i covers elems 2i,2i+1 of node (2i)/64
        __half2 v = s[i];
        float a = __half2float(__low2half(v)) * isv;
        float b = __half2float(__high2half(v)) * isv;
        d[i] = __halves2half2(__float2half(a), __float2half(b));
    }
}

// -------- propagation: h = 0.9*is[d]*sum(u[src]) + alpha*h0; u_out = h*is[d] --
__global__ __launch_bounds__(256) void prop_kernel(const int* __restrict__ rowptr,
                                                   const int* __restrict__ csr_src,
                                                   const float* __restrict__ is,
                                                   const __half* __restrict__ u_in,
                                                   const __half* __restrict__ h0h,
                                                   __half* __restrict__ u_out,
                                                   float* __restrict__ out_f32,
                                                   int N, int last) {
    int wid = (blockIdx.x * blockDim.x + threadIdx.x) >> 6;
    int lane = threadIdx.x & 63;
    if (wid >= N) return;
    int base = rowptr[wid];
    int end = rowptr[wid + 1];
    float acc = 0.0f;
    for (int b = base; b < end; b += 64) {
        int m = end - b;
        if (m > 64) m = 64;
        int s = (lane < m) ? csr_src[b + lane] : 0;
        int t = 0;
        for (; t + 8 <= m; t += 8) {
            int ss[8];
            float v[8];
#pragma unroll
            for (int j = 0; j < 8; ++j) ss[j] = __shfl(s, t + j);
#pragma unroll
            for (int j = 0; j < 8; ++j) v[j] = __half2float(u_in[(size_t)ss[j] * CLASSES + lane]);
#pragma unroll
            for (int j = 0; j < 8; ++j) acc += v[j];
        }
        for (; t < m; ++t) {
            int ss = __shfl(s, t);
            acc += __half2float(u_in[(size_t)ss * CLASSES + lane]);
        }
    }
    float isd = is[wid];
    size_t o = (size_t)wid * CLASSES + lane;
    float h = (1.0f - ALPHA) * isd * acc + ALPHA * __half2float(h0h[o]);
    if (last) out_f32[o] = h;
    else u_out[o] = __float2half(h * isd);
}

extern "C" void kernel_launch(void* const* d_in, const int* in_sizes, int n_in,
                              void* d_out, int out_size, void* d_ws, size_t ws_size,
                              hipStream_t stream) {
    const float* x = (const float*)d_in[0];
    const int* edges = (const int*)d_in[1];
    const float* W1 = (const float*)d_in[2];
    const float* b1 = (const float*)d_in[3];
    const float* W2 = (const float*)d_in[4];
    const float* b2 = (const float*)d_in[5];
    float* out = (float*)d_out;

    const int N = in_sizes[0] / FEATS;   // 100000
    const int E = in_sizes[1] / 2;       // 1600000
    const int NB = (N + 63) >> 6;        // 1563
    const int* src = edges;
    const int* dst = edges + E;

    char* ws = (char*)d_ws;
    size_t off = 0;
    auto alloc = [&](size_t bytes) {
        char* p = ws + off;
        off = (off + bytes + 255) & ~(size_t)255;
        return p;
    };
    int2* part = (int2*)alloc((size_t)E * 8);
    int* csr_src = (int*)alloc((size_t)E * 4);
    int* bcnt = (int*)alloc((size_t)NB * 4);
    int* bptr = (int*)alloc((size_t)(NB + 1) * 4);
    int* gcur = (int*)alloc((size_t)NB * 4);
    int* rowptr = (int*)alloc((size_t)(N + 1) * 4);
    float* inv_sqrt = (float*)alloc((size_t)N * 4);
    __half* h0h = (__half*)alloc((size_t)N * CLASSES * 2);
    __half* uA = (__half*)alloc((size_t)N * CLASSES * 2);
    __half* uB = (__half*)alloc((size_t)N * CLASSES * 2);
    unsigned short* w1h = (unsigned short*)alloc(4096 * 8 * 2);
    unsigned short* w1l = (unsigned short*)alloc(4096 * 8 * 2);
    unsigned short* w2h = (unsigned short*)alloc(512 * 8 * 2);
    unsigned short* w2l = (unsigned short*)alloc(512 * 8 * 2);
    (void)ws_size;

    // ---- CSR build (two-level bucket sort) ----
    hipMemsetAsync(bcnt, 0, (size_t)NB * 4, stream);
    bucket_hist_kernel<<<128, 256, 0, stream>>>(dst, bcnt, NB, E);
    bucket_scan_kernel<<<1, 1024, 0, stream>>>(bcnt, bptr, gcur, rowptr, NB, N, E);
    int k3_blocks = (E + K3_CHUNK - 1) / K3_CHUNK;
    bucket_scatter_kernel<<<k3_blocks, K3_THREADS, 0, stream>>>(src, dst, gcur, part, NB, E);
    part_to_csr_kernel<<<NB, 128, 0, stream>>>(bptr, part, rowptr, inv_sqrt, csr_src, N);

    // ---- MLP -> h0 (fp16) ----
    pack_w_kernel<<<18, 256, 0, stream>>>(W1, W2, w1h, w1l, w2h, w2l);
    int tiles = (N + 15) / 16;
    mlp_mfma_kernel<<<(tiles + 3) / 4, 256, 0, stream>>>(x, w1h, w1l, b1, w2h, w2l, b2, h0h, N);

    // ---- u0 = h0 * inv_sqrt ----
    u0_kernel<<<2048, 256, 0, stream>>>(h0h, inv_sqrt, uA, N * CLASSES / 2);

    // ---- 10 propagation rounds ----
    int blocks = (N * 64 + 255) / 256;
    for (int d = 0; d < DEPTH; ++d) {
        const __half* uin = (d & 1) ? uB : uA;
        __half* uout = (d & 1) ? uA : uB;
        int last = (d == DEPTH - 1);
        prop_kernel<<<blocks, 256, 0, stream>>>(rowptr, csr_src, inv_sqrt, uin, h0h,
                                                uout, out, N, last);
    }
}

// Round 4
// 607.003 us; speedup vs baseline: 2.6906x; 1.1261x over previous
//
#include <hip/hip_runtime.h>
#include <hip/hip_fp16.h>

#define FEATS 512
#define HIDDEN 64
#define CLASSES 64
#define DEPTH 10
#define ALPHA 0.1f

#define NB_C 1563        // ceil(100000 / 64) buckets of 64 nodes
#define K3_CHUNK 8192
#define K3_THREADS 512

typedef __attribute__((ext_vector_type(8))) short short8;
typedef __attribute__((ext_vector_type(4))) float f32x4;

__device__ __forceinline__ unsigned short bf16_hi(float f) {
    unsigned u = __float_as_uint(f);
    unsigned r = u + 0x7FFF + ((u >> 16) & 1);   // RNE
    return (unsigned short)(r >> 16);
}
__device__ __forceinline__ float bf16_tof(unsigned short h) {
    return __uint_as_float(((unsigned)h) << 16);
}

// ---------------- K1: bucket histogram (LDS-aggregated) ----------------
__global__ __launch_bounds__(256) void bucket_hist_kernel(const int* __restrict__ dst,
                                                          int* __restrict__ bcnt,
                                                          int NB, int E) {
    __shared__ int h[NB_C];
    for (int j = threadIdx.x; j < NB; j += 256) h[j] = 0;
    __syncthreads();
    int i = blockIdx.x * 256 + threadIdx.x;
    int stride = gridDim.x * 256;
    for (; i < E; i += stride) atomicAdd(&h[dst[i] >> 6], 1);
    __syncthreads();
    for (int j = threadIdx.x; j < NB; j += 256) {
        int v = h[j];
        if (v) atomicAdd(&bcnt[j], v);
    }
}

// ---------------- K2: scan bucket counts -> bptr, gcursor ----------------
__global__ __launch_bounds__(1024) void bucket_scan_kernel(const int* __restrict__ bcnt,
                                                           int* __restrict__ bptr,
                                                           int* __restrict__ gcur,
                                                           int* __restrict__ rowptr,
                                                           int NB, int N, int E) {
    __shared__ int sd[1024];
    int t = threadIdx.x;
    int i0 = 2 * t, i1 = 2 * t + 1;
    int a = (i0 < NB) ? bcnt[i0] : 0;
    int b = (i1 < NB) ? bcnt[i1] : 0;
    int s = a + b;
    sd[t] = s;
    __syncthreads();
    for (int off = 1; off < 1024; off <<= 1) {
        int v = (t >= off) ? sd[t - off] : 0;
        __syncthreads();
        sd[t] += v;
        __syncthreads();
    }
    int excl = sd[t] - s;
    if (i0 < NB) { bptr[i0] = excl;     gcur[i0] = excl; }
    if (i1 < NB) { bptr[i1] = excl + a; gcur[i1] = excl + a; }
    if (t == 0) { bptr[NB] = E; rowptr[N] = E; }
}

// ---------------- K3: partition edges into buckets (packed src|ldst) ----------
__global__ __launch_bounds__(K3_THREADS) void bucket_scatter_kernel(const int* __restrict__ src,
                                                                    const int* __restrict__ dst,
                                                                    int* __restrict__ gcur,
                                                                    int* __restrict__ part,
                                                                    int NB, int E) {
    __shared__ int hist[NB_C];
    __shared__ int base[NB_C];
    int cbase = blockIdx.x * K3_CHUNK;
    for (int j = threadIdx.x; j < NB; j += K3_THREADS) hist[j] = 0;
    __syncthreads();
    for (int k = 0; k < K3_CHUNK; k += K3_THREADS) {
        int i = cbase + k + threadIdx.x;
        if (i < E) atomicAdd(&hist[dst[i] >> 6], 1);
    }
    __syncthreads();
    for (int j = threadIdx.x; j < NB; j += K3_THREADS) {
        int h = hist[j];
        base[j] = (h > 0) ? atomicAdd(&gcur[j], h) : 0;
        hist[j] = 0;   // reuse as local cursor
    }
    __syncthreads();
    for (int k = 0; k < K3_CHUNK; k += K3_THREADS) {
        int i = cbase + k + threadIdx.x;
        if (i < E) {
            int d = dst[i];
            int j = d >> 6;
            int off = atomicAdd(&hist[j], 1);
            part[(size_t)(base[j] + off)] = (src[i] << 6) | (d & 63);
        }
    }
}

// ---------------- K4: per-bucket exact CSR + degrees + inv_sqrt ----------------
__global__ __launch_bounds__(128) void part_to_csr_kernel(const int* __restrict__ bptr,
                                                          const int* __restrict__ part,
                                                          int* __restrict__ rowptr,
                                                          float* __restrict__ inv_sqrt,
                                                          int* __restrict__ csr_src,
                                                          int N) {
    __shared__ int cnt[64];
    __shared__ int cur[64];
    int b = blockIdx.x;
    int lo = b << 6;
    int tid = threadIdx.x;
    int p0 = bptr[b], p1 = bptr[b + 1];
    if (tid < 64) cnt[tid] = 0;
    __syncthreads();
    for (int i = p0 + tid; i < p1; i += 128) {
        atomicAdd(&cnt[part[i] & 63], 1);
    }
    __syncthreads();
    if (tid < 64) {
        int v = cnt[tid];
        int incl = v;
#pragma unroll
        for (int off = 1; off < 64; off <<= 1) {
            int t = __shfl_up(incl, off);
            if (tid >= off) incl += t;
        }
        int excl = incl - v;
        if (lo + tid < N) {
            rowptr[lo + tid] = p0 + excl;
            inv_sqrt[lo + tid] = rsqrtf((float)(v < 1 ? 1 : v));
        }
        cur[tid] = excl;
    }
    __syncthreads();
    for (int i = p0 + tid; i < p1; i += 128) {
        int pe = part[i];
        int off = atomicAdd(&cur[pe & 63], 1);
        csr_src[p0 + off] = ((unsigned)pe) >> 6;
    }
}

// ---------------- pack W1/W2 into MFMA B-fragment order, split bf16 hi/lo ----
__global__ __launch_bounds__(256) void pack_w_kernel(const float* __restrict__ W1,
                                                     const float* __restrict__ W2,
                                                     unsigned short* __restrict__ w1h,
                                                     unsigned short* __restrict__ w1l,
                                                     unsigned short* __restrict__ w2h,
                                                     unsigned short* __restrict__ w2l) {
    int id = blockIdx.x * blockDim.x + threadIdx.x;
    if (id < 4096) {
        int lane = id & 63, f = (id >> 6) & 3, ks = id >> 8;
        int col = f * 16 + (lane & 15);
        int k0 = ks * 32 + (lane >> 4) * 8;
#pragma unroll
        for (int i = 0; i < 8; ++i) {
            float v = W1[(k0 + i) * HIDDEN + col];
            unsigned short h = bf16_hi(v);
            w1h[id * 8 + i] = h;
            w1l[id * 8 + i] = bf16_hi(v - bf16_tof(h));
        }
    } else if (id < 4096 + 512) {
        int p = id - 4096;
        int lane = p & 63, f = (p >> 6) & 3, ks = p >> 8;
        int col = f * 16 + (lane & 15);
        int k0 = ks * 32 + (lane >> 4) * 8;
#pragma unroll
        for (int i = 0; i < 8; ++i) {
            float v = W2[(k0 + i) * CLASSES + col];
            unsigned short h = bf16_hi(v);
            w2h[p * 8 + i] = h;
            w2l[p * 8 + i] = bf16_hi(v - bf16_tof(h));
        }
    }
}

// ------- MLP via split-bf16 MFMA: h0 = relu(x@W1+b1)@W2+b2; also u0 = h0*is --
__global__ __launch_bounds__(256) void mlp_mfma_kernel(const float* __restrict__ x,
                                                       const unsigned short* __restrict__ w1h,
                                                       const unsigned short* __restrict__ w1l,
                                                       const float* __restrict__ b1,
                                                       const unsigned short* __restrict__ w2h,
                                                       const unsigned short* __restrict__ w2l,
                                                       const float* __restrict__ b2,
                                                       const float* __restrict__ is,
                                                       __half* __restrict__ h0h,
                                                       __half* __restrict__ u0,
                                                       int N) {
    __shared__ float hs[4][16][68];
    int wave = threadIdx.x >> 6;
    int lane = threadIdx.x & 63;
    int tile = blockIdx.x * 4 + wave;
    if (tile * 16 >= N) return;

    int row = lane & 15;
    int koff = (lane >> 4) * 8;
    const short8* w1hv = (const short8*)w1h;
    const short8* w1lv = (const short8*)w1l;
    const short8* w2hv = (const short8*)w2h;
    const short8* w2lv = (const short8*)w2l;

    f32x4 c[4] = {};
    const float* xrow = x + (size_t)(tile * 16 + row) * FEATS + koff;
#pragma unroll 4
    for (int ks = 0; ks < 16; ++ks) {
        float4 a0 = *(const float4*)(xrow + ks * 32);
        float4 a1 = *(const float4*)(xrow + ks * 32 + 4);
        float av[8] = {a0.x, a0.y, a0.z, a0.w, a1.x, a1.y, a1.z, a1.w};
        short8 ah, al;
#pragma unroll
        for (int j = 0; j < 8; ++j) {
            unsigned short h = bf16_hi(av[j]);
            ah[j] = (short)h;
            al[j] = (short)bf16_hi(av[j] - bf16_tof(h));
        }
#pragma unroll
        for (int f = 0; f < 4; ++f) {
            short8 bh = w1hv[(ks * 4 + f) * 64 + lane];
            short8 bl = w1lv[(ks * 4 + f) * 64 + lane];
            c[f] = __builtin_amdgcn_mfma_f32_16x16x32_bf16(ah, bh, c[f], 0, 0, 0);
            c[f] = __builtin_amdgcn_mfma_f32_16x16x32_bf16(ah, bl, c[f], 0, 0, 0);
            c[f] = __builtin_amdgcn_mfma_f32_16x16x32_bf16(al, bh, c[f], 0, 0, 0);
        }
    }
#pragma unroll
    for (int f = 0; f < 4; ++f) {
        float bias = b1[f * 16 + (lane & 15)];
#pragma unroll
        for (int r = 0; r < 4; ++r) {
            hs[wave][(lane >> 4) * 4 + r][f * 16 + (lane & 15)] = fmaxf(c[f][r] + bias, 0.0f);
        }
    }

    f32x4 c2[4] = {};
#pragma unroll
    for (int ks = 0; ks < 2; ++ks) {
        float4 a0 = *(const float4*)&hs[wave][row][ks * 32 + koff];
        float4 a1 = *(const float4*)&hs[wave][row][ks * 32 + koff + 4];
        float av[8] = {a0.x, a0.y, a0.z, a0.w, a1.x, a1.y, a1.z, a1.w};
        short8 ah, al;
#pragma unroll
        for (int j = 0; j < 8; ++j) {
            unsigned short h = bf16_hi(av[j]);
            ah[j] = (short)h;
            al[j] = (short)bf16_hi(av[j] - bf16_tof(h));
        }
#pragma unroll
        for (int f = 0; f < 4; ++f) {
            short8 bh = w2hv[(ks * 4 + f) * 64 + lane];
            short8 bl = w2lv[(ks * 4 + f) * 64 + lane];
            c2[f] = __builtin_amdgcn_mfma_f32_16x16x32_bf16(ah, bh, c2[f], 0, 0, 0);
            c2[f] = __builtin_amdgcn_mfma_f32_16x16x32_bf16(ah, bl, c2[f], 0, 0, 0);
            c2[f] = __builtin_amdgcn_mfma_f32_16x16x32_bf16(al, bh, c2[f], 0, 0, 0);
        }
    }
    float isv[4];
#pragma unroll
    for (int r = 0; r < 4; ++r) {
        int n = tile * 16 + (lane >> 4) * 4 + r;
        isv[r] = is[n];
    }
#pragma unroll
    for (int f = 0; f < 4; ++f) {
        float bias = b2[f * 16 + (lane & 15)];
#pragma unroll
        for (int r = 0; r < 4; ++r) {
            int n = tile * 16 + (lane >> 4) * 4 + r;
            float v = c2[f][r] + bias;
            h0h[(size_t)n * CLASSES + f * 16 + (lane & 15)] = __float2half(v);
            u0[(size_t)n * CLASSES + f * 16 + (lane & 15)] = __float2half(v * isv[r]);
        }
    }
}

// -------- propagation: h = 0.9*is[d]*sum(u[src]) + alpha*h0; u_out = h*is[d] --
// wave per node; grp=lane>>3 selects edge, sub=lane&7 selects 8-feature slice:
// one dwordx4 gathers 8 full rows per wave-instruction.
__global__ __launch_bounds__(256) void prop_kernel(const int* __restrict__ rowptr,
                                                   const int* __restrict__ csr_src,
                                                   const float* __restrict__ is,
                                                   const __half* __restrict__ u_in,
                                                   const __half* __restrict__ h0h,
                                                   __half* __restrict__ u_out,
                                                   float* __restrict__ out_f32,
                                                   int N, int last) {
    int wid = (blockIdx.x * blockDim.x + threadIdx.x) >> 6;
    int lane = threadIdx.x & 63;
    if (wid >= N) return;
    int base = rowptr[wid];
    int end = rowptr[wid + 1];
    int grp = lane >> 3, sub = lane & 7;
    float acc[8] = {0.f, 0.f, 0.f, 0.f, 0.f, 0.f, 0.f, 0.f};
    for (int b = base; b < end; b += 16) {
        int e0 = b + grp;
        int e1 = e0 + 8;
        bool v0 = e0 < end;
        bool v1 = e1 < end;
        int s0 = csr_src[v0 ? e0 : base];
        int s1 = csr_src[v1 ? e1 : base];
        uint4 q0 = *(const uint4*)(u_in + ((size_t)s0 << 6) + (sub << 3));
        uint4 q1 = *(const uint4*)(u_in + ((size_t)s1 << 6) + (sub << 3));
        if (v0) {
            const __half2* hp = (const __half2*)&q0;
#pragma unroll
            for (int k = 0; k < 4; ++k) {
                float2 f2 = __half22float2(hp[k]);
                acc[2 * k] += f2.x;
                acc[2 * k + 1] += f2.y;
            }
        }
        if (v1) {
            const __half2* hp = (const __half2*)&q1;
#pragma unroll
            for (int k = 0; k < 4; ++k) {
                float2 f2 = __half22float2(hp[k]);
                acc[2 * k] += f2.x;
                acc[2 * k + 1] += f2.y;
            }
        }
    }
#pragma unroll
    for (int j = 0; j < 8; ++j) {
        acc[j] += __shfl_xor(acc[j], 8);
        acc[j] += __shfl_xor(acc[j], 16);
        acc[j] += __shfl_xor(acc[j], 32);
    }
    if (grp == 0) {
        float isd = is[wid];
        size_t rowo = ((size_t)wid << 6) + (sub << 3);
        uint4 hq = *(const uint4*)(h0h + rowo);
        const __half2* hp = (const __half2*)&hq;
        float h[8];
#pragma unroll
        for (int k = 0; k < 4; ++k) {
            float2 f2 = __half22float2(hp[k]);
            h[2 * k] = f2.x;
            h[2 * k + 1] = f2.y;
        }
        if (last) {
            float r[8];
#pragma unroll
            for (int j = 0; j < 8; ++j) r[j] = (1.0f - ALPHA) * isd * acc[j] + ALPHA * h[j];
            *(float4*)(out_f32 + rowo) = make_float4(r[0], r[1], r[2], r[3]);
            *(float4*)(out_f32 + rowo + 4) = make_float4(r[4], r[5], r[6], r[7]);
        } else {
            __half2 w[4];
#pragma unroll
            for (int k = 0; k < 4; ++k) {
                float a = ((1.0f - ALPHA) * isd * acc[2 * k] + ALPHA * h[2 * k]) * isd;
                float b = ((1.0f - ALPHA) * isd * acc[2 * k + 1] + ALPHA * h[2 * k + 1]) * isd;
                w[k] = __floats2half2_rn(a, b);
            }
            *(uint4*)(u_out + rowo) = *(uint4*)w;
        }
    }
}

extern "C" void kernel_launch(void* const* d_in, const int* in_sizes, int n_in,
                              void* d_out, int out_size, void* d_ws, size_t ws_size,
                              hipStream_t stream) {
    const float* x = (const float*)d_in[0];
    const int* edges = (const int*)d_in[1];
    const float* W1 = (const float*)d_in[2];
    const float* b1 = (const float*)d_in[3];
    const float* W2 = (const float*)d_in[4];
    const float* b2 = (const float*)d_in[5];
    float* out = (float*)d_out;

    const int N = in_sizes[0] / FEATS;   // 100000
    const int E = in_sizes[1] / 2;       // 1600000
    const int NB = (N + 63) >> 6;        // 1563
    const int* src = edges;
    const int* dst = edges + E;

    char* ws = (char*)d_ws;
    size_t off = 0;
    auto alloc = [&](size_t bytes) {
        char* p = ws + off;
        off = (off + bytes + 255) & ~(size_t)255;
        return p;
    };
    int* part = (int*)alloc((size_t)E * 4);
    int* csr_src = (int*)alloc((size_t)E * 4);
    int* bcnt = (int*)alloc((size_t)NB * 4);
    int* bptr = (int*)alloc((size_t)(NB + 1) * 4);
    int* gcur = (int*)alloc((size_t)NB * 4);
    int* rowptr = (int*)alloc((size_t)(N + 1) * 4);
    float* inv_sqrt = (float*)alloc((size_t)N * 4);
    __half* h0h = (__half*)alloc((size_t)N * CLASSES * 2);
    __half* uA = (__half*)alloc((size_t)N * CLASSES * 2);
    __half* uB = (__half*)alloc((size_t)N * CLASSES * 2);
    unsigned short* w1h = (unsigned short*)alloc(4096 * 8 * 2);
    unsigned short* w1l = (unsigned short*)alloc(4096 * 8 * 2);
    unsigned short* w2h = (unsigned short*)alloc(512 * 8 * 2);
    unsigned short* w2l = (unsigned short*)alloc(512 * 8 * 2);
    (void)ws_size;

    // ---- CSR build (two-level bucket sort) ----
    hipMemsetAsync(bcnt, 0, (size_t)NB * 4, stream);
    bucket_hist_kernel<<<128, 256, 0, stream>>>(dst, bcnt, NB, E);
    bucket_scan_kernel<<<1, 1024, 0, stream>>>(bcnt, bptr, gcur, rowptr, NB, N, E);
    int k3_blocks = (E + K3_CHUNK - 1) / K3_CHUNK;
    bucket_scatter_kernel<<<k3_blocks, K3_THREADS, 0, stream>>>(src, dst, gcur, part, NB, E);
    part_to_csr_kernel<<<NB, 128, 0, stream>>>(bptr, part, rowptr, inv_sqrt, csr_src, N);

    // ---- MLP -> h0 (fp16) + u0 = h0*is ----
    pack_w_kernel<<<18, 256, 0, stream>>>(W1, W2, w1h, w1l, w2h, w2l);
    int tiles = (N + 15) / 16;
    mlp_mfma_kernel<<<(tiles + 3) / 4, 256, 0, stream>>>(x, w1h, w1l, b1, w2h, w2l, b2,
                                                         inv_sqrt, h0h, uA, N);

    // ---- 10 propagation rounds ----
    int blocks = (N * 64 + 255) / 256;
    for (int d = 0; d < DEPTH; ++d) {
        const __half* uin = (d & 1) ? uB : uA;
        __half* uout = (d & 1) ? uA : uB;
        int last = (d == DEPTH - 1);
        prop_kernel<<<blocks, 256, 0, stream>>>(rowptr, csr_src, inv_sqrt, uin, h0h,
                                                uout, out, N, last);
    }
}